// Round 6
// baseline (1380.534 us; speedup 1.0000x reference)
//
#include <hip/hip_runtime.h>
#include <hip/hip_bf16.h>
#include <stdint.h>

// Problem constants: H=2048, I=4096, E=8, TOPK=2, B*S=4096
#define H_DIM 2048
#define I_DIM 4096
#define NEXP  8
#define NTOK  4096
#define NPAIR 8192
#define PAD_ROWS (NPAIR + 256)

// Workspace layout (bytes)
#define MiB (1024ull * 1024ull)
#define WS_COUNTS   0ull
#define WS_OFFSETS  256ull
#define WS_TOKID    1024ull
#define WS_SLOT     (64ull * 1024)
#define WS_PAIRW    (128ull * 1024)
#define WS_XG       (1ull * MiB)            // PAD_ROWS*H*2B = 34.6 MB
#define WS_INTER    (36ull * MiB)           // PAD_ROWS*I*2B = 69.2 MB
#define WS_Y        (104ull * MiB)          // PAD_ROWS*H*4B = 69.2 MB
#define WS_GW       (176ull * MiB)          // E*I*H bf16 = 128 MiB
#define WS_UW       (304ull * MiB)
#define WS_DW       (432ull * MiB)
#define WS_FULL     (560ull * MiB)

typedef __attribute__((ext_vector_type(8))) short bf16x8;
typedef __attribute__((ext_vector_type(4))) float f32x4;

#if defined(__has_builtin)
#if __has_builtin(__builtin_amdgcn_cvt_pk_bf16_f32)
#define HAVE_CVT_PK 1
#endif
#endif

__device__ __forceinline__ uint32_t bf16_bits_rne(float x) {
  uint32_t u = __float_as_uint(x);
  return (u + 0x7FFFu + ((u >> 16) & 1u)) >> 16;
}
__device__ __forceinline__ uint32_t pk_bf16(float a, float b) {
#ifdef HAVE_CVT_PK
  auto r = __builtin_amdgcn_cvt_pk_bf16_f32(a, b);
  return __builtin_bit_cast(uint32_t, r);
#else
  return bf16_bits_rne(a) | (bf16_bits_rne(b) << 16);
#endif
}
__device__ __forceinline__ uint16_t bf16_one(float x) {
  return (uint16_t)(pk_bf16(x, x) & 0xFFFFu);
}

// async global->LDS, 16B/lane: lane i lands at lds_base + 16*i (base wave-uniform)
__device__ __forceinline__ void async_load16(const void* g, void* l) {
  __builtin_amdgcn_global_load_lds(
      (const __attribute__((address_space(1))) void*)g,
      (__attribute__((address_space(3))) void*)l, 16, 0, 0);
}

#define WAIT_VM6()   do { asm volatile("s_waitcnt vmcnt(6)" ::: "memory"); __builtin_amdgcn_sched_barrier(0); } while (0)
#define WAIT_VM0()   do { asm volatile("s_waitcnt vmcnt(0)" ::: "memory"); __builtin_amdgcn_sched_barrier(0); } while (0)
#define WAIT_LGKM0() do { asm volatile("s_waitcnt lgkmcnt(0)" ::: "memory"); __builtin_amdgcn_sched_barrier(0); } while (0)
#define BARRIER()    do { __builtin_amdgcn_s_barrier(); asm volatile("" ::: "memory"); } while (0)

// ---------------- routing ----------------
__global__ void route_kernel(const int* __restrict__ idx, const float* __restrict__ wts,
                             int* __restrict__ ws_counts, int* __restrict__ ws_offsets,
                             int* __restrict__ tokid, int* __restrict__ slotOf,
                             float* __restrict__ pairw) {
  __shared__ int s_cnt[NEXP], s_off[NEXP], s_cur[NEXP];
  int tid = threadIdx.x;
  if (tid < NEXP) s_cnt[tid] = 0;
  __syncthreads();
  for (int p = tid; p < NPAIR; p += 256) atomicAdd(&s_cnt[idx[p]], 1);
  __syncthreads();
  if (tid == 0) {
    int acc = 0;
    for (int e = 0; e < NEXP; e++) { s_off[e] = acc; s_cur[e] = acc; acc += s_cnt[e]; }
  }
  __syncthreads();
  for (int p = tid; p < NPAIR; p += 256) {
    int e = idx[p];
    int slot = atomicAdd(&s_cur[e], 1);
    tokid[slot] = p >> 1;
    slotOf[p] = slot;
    pairw[slot] = wts[p];
  }
  if (tid < NEXP) { ws_counts[tid] = s_cnt[tid]; ws_offsets[tid] = s_off[tid]; }
}

// ---------------- gather routed rows of x, fp32 -> bf16 ----------------
__global__ void gather_cast_kernel(const float* __restrict__ x, const int* __restrict__ tokid,
                                   uint16_t* __restrict__ xg) {
  int p = blockIdx.x;
  int t = tokid[p];
  int c = threadIdx.x * 8;
  const float4* src = (const float4*)(x + (size_t)t * H_DIM + c);
  float4 v0 = src[0], v1 = src[1];
  uint4 o;
  o.x = pk_bf16(v0.x, v0.y); o.y = pk_bf16(v0.z, v0.w);
  o.z = pk_bf16(v1.x, v1.y); o.w = pk_bf16(v1.z, v1.w);
  *(uint4*)(xg + (size_t)p * H_DIM + c) = o;
}

// ---------------- one-shot weight cast fp32 -> bf16 ----------------
__global__ void cast3_kernel(const float* __restrict__ g, const float* __restrict__ u,
                             const float* __restrict__ d,
                             uint16_t* __restrict__ gw, uint16_t* __restrict__ uw,
                             uint16_t* __restrict__ dw) {
  const float* src = blockIdx.y == 0 ? g : (blockIdx.y == 1 ? u : d);
  uint16_t*    dst = blockIdx.y == 0 ? gw : (blockIdx.y == 1 ? uw : dw);
  const long long n8 = (long long)NEXP * I_DIM * H_DIM / 8;
  long long stride = (long long)gridDim.x * blockDim.x;
  for (long long i = (long long)blockIdx.x * blockDim.x + threadIdx.x; i < n8; i += stride) {
    const float4* s = (const float4*)(src + i * 8);
    float4 a = s[0], b = s[1];
    uint4 o = { pk_bf16(a.x, a.y), pk_bf16(a.z, a.w), pk_bf16(b.x, b.y), pk_bf16(b.z, b.w) };
    *(uint4*)(dst + i * 8) = o;
  }
}

// =====================================================================================
// GEMM1 v6 = v2 schedule (proven 356 us: 256x64-dual tile, BK=64, 8 waves 4Mx2N,
// triple-buffered LDS, source-side XOR swizzle -> 0 bank conflicts, counted vmcnt(6),
// one barrier per K-tile) + XCD-chunked blockIdx swizzle: each XCD owns one expert's
// contiguous (col, rowTile) space so shared A-panels are XCD-L2-local.
// =====================================================================================
#define T1_A    (256 * 64)
#define T1_B    (64 * 64)
#define T1_ELE  (T1_A + 2 * T1_B)   // 24576 elems = 48KB

__global__ __launch_bounds__(512, 1)
void gemm1_v6(const uint16_t* __restrict__ xg,
              const uint16_t* __restrict__ gw, const uint16_t* __restrict__ uw,
              const int* __restrict__ ws_counts, const int* __restrict__ ws_offsets,
              uint16_t* __restrict__ inter) {
  // XCD swizzle: nwg = 64*32*8 = 16384, cpx = 2048 (= one expert per XCD chunk)
  int lin = blockIdx.x;
  int wid = (lin & 7) * 2048 + (lin >> 3);
  int bx = wid & 63;                 // col panel (fastest -> A-panel sharing within XCD)
  int by = (wid >> 6) & 31;          // rowTile
  int e  = wid >> 11;                // expert

  int cnt = ws_counts[e];
  if (by * 256 >= cnt) return;
  int off = ws_offsets[e];
  int colBase = bx * 64;
  size_t rowBase = (size_t)off + (size_t)by * 256;

  __shared__ uint16_t lds[3 * T1_ELE];    // 144 KB

  int tid = threadIdx.x, lane = tid & 63, w = tid >> 6;
  int r8 = lane >> 3;
  int gsw = ((lane & 7) ^ r8) << 3;        // pre-swizzled source col (elements)

  const uint16_t* srcA[4];
#pragma unroll
  for (int c = 0; c < 4; c++)
    srcA[c] = xg + (rowBase + (size_t)(w * 32 + c * 8 + r8)) * H_DIM + gsw;
  const uint16_t* srcG = gw + ((size_t)e * I_DIM + colBase + w * 8 + r8) * H_DIM + gsw;
  const uint16_t* srcU = uw + ((size_t)e * I_DIM + colBase + w * 8 + r8) * H_DIM + gsw;

  const int dA = w * 2048;
  const int dG = T1_A + w * 512;
  const int dU = T1_A + T1_B + w * 512;

  f32x4 accg[4][2], accu[4][2];
  f32x4 zero = {0.f, 0.f, 0.f, 0.f};
#pragma unroll
  for (int mi = 0; mi < 4; mi++)
#pragma unroll
    for (int ni = 0; ni < 2; ni++) { accg[mi][ni] = zero; accu[mi][ni] = zero; }

  auto STG = [&](int kt, int b) {
    uint16_t* lb = lds + b * T1_ELE;
    int ko = kt * 64;
#pragma unroll
    for (int c = 0; c < 4; c++) async_load16(srcA[c] + ko, lb + dA + c * 512);
    async_load16(srcG + ko, lb + dG);
    async_load16(srcU + ko, lb + dU);
  };

  STG(0, 0); STG(1, 1);
  WAIT_VM6();
  BARRIER();

  int wr = w >> 1, wc = w & 1;
  int wm = wr * 64, wn = wc * 32;
  int lcol = lane & 15, quad = lane >> 4;
  int sx = (lcol & 7) << 3;

  const int NT = H_DIM / 64;               // 32
  for (int t = 0; t < NT; ++t) {
    if (t + 2 < NT) STG(t + 2, (t + 2) % 3);
    const uint16_t* lb = lds + (t % 3) * T1_ELE;
#pragma unroll
    for (int ks = 0; ks < 2; ks++) {
      int krs = (ks * 32 + quad * 8) ^ sx;
      bf16x8 af[4], bg_[2], bu_[2];
#pragma unroll
      for (int mi = 0; mi < 4; mi++)
        af[mi] = *(const bf16x8*)(lb + (wm + mi * 16 + lcol) * 64 + krs);
#pragma unroll
      for (int ni = 0; ni < 2; ni++) {
        bg_[ni] = *(const bf16x8*)(lb + T1_A + (wn + ni * 16 + lcol) * 64 + krs);
        bu_[ni] = *(const bf16x8*)(lb + T1_A + T1_B + (wn + ni * 16 + lcol) * 64 + krs);
      }
      __builtin_amdgcn_s_setprio(1);
#pragma unroll
      for (int mi = 0; mi < 4; mi++)
#pragma unroll
        for (int ni = 0; ni < 2; ni++) {
          accg[mi][ni] = __builtin_amdgcn_mfma_f32_16x16x32_bf16(af[mi], bg_[ni], accg[mi][ni], 0, 0, 0);
          accu[mi][ni] = __builtin_amdgcn_mfma_f32_16x16x32_bf16(af[mi], bu_[ni], accu[mi][ni], 0, 0, 0);
        }
      __builtin_amdgcn_s_setprio(0);
    }
    if (t + 2 < NT) { WAIT_VM6(); } else { WAIT_VM0(); }
    BARRIER();
  }

  // epilogue: silu(g)*u -> bf16 inter.  C layout: col=lane&15, row=quad*4+reg
  int col0 = colBase + wn;
#pragma unroll
  for (int mi = 0; mi < 4; mi++) {
#pragma unroll
    for (int r = 0; r < 4; r++) {
      int localRow = by * 256 + wm + mi * 16 + quad * 4 + r;
      if (localRow < cnt) {
        size_t prow = (size_t)off + localRow;
#pragma unroll
        for (int ni = 0; ni < 2; ni++) {
          float g = accg[mi][ni][r], u = accu[mi][ni][r];
          float v = (g / (1.f + __expf(-g))) * u;
          inter[prow * I_DIM + col0 + ni * 16 + lcol] = bf16_one(v);
        }
      }
    }
  }
}

// =====================================================================================
// GEMM2 v6 = v5 2-phase schedule (best measured for gemm2) + XCD-chunked swizzle.
// tile 256x128, BK=64, triple-buffered, counted vmcnt(6).
// =====================================================================================
#define T2_A    (256 * 64)
#define T2_B    (128 * 64)
#define T2_ELE  (T2_A + T2_B)       // 24576 elems = 48KB

__global__ __launch_bounds__(512, 1)
void gemm2_v6(const uint16_t* __restrict__ inter, const uint16_t* __restrict__ dw,
              const int* __restrict__ ws_counts, const int* __restrict__ ws_offsets,
              const float* __restrict__ pairw, float* __restrict__ y) {
  // XCD swizzle: nwg = 16*32*8 = 4096, cpx = 512 (= one expert per XCD chunk)
  int lin = blockIdx.x;
  int wid = (lin & 7) * 512 + (lin >> 3);
  int bx = wid & 15;
  int by = (wid >> 4) & 31;
  int e  = wid >> 9;

  int cnt = ws_counts[e];
  if (by * 256 >= cnt) return;
  int off = ws_offsets[e];
  int colBase = bx * 128;
  size_t rowBase = (size_t)off + (size_t)by * 256;

  __shared__ uint16_t lds[3 * T2_ELE];    // 144 KB

  int tid = threadIdx.x, lane = tid & 63, w = tid >> 6;
  int r8 = lane >> 3;
  int gsw = ((lane & 7) ^ r8) << 3;

  const uint16_t* srcA[4];
#pragma unroll
  for (int c = 0; c < 4; c++)
    srcA[c] = inter + (rowBase + (size_t)(w * 32 + c * 8 + r8)) * I_DIM + gsw;
  const uint16_t* srcB[2];
#pragma unroll
  for (int c = 0; c < 2; c++)
    srcB[c] = dw + ((size_t)e * H_DIM + colBase + w * 16 + c * 8 + r8) * I_DIM + gsw;

  const int dA = w * 2048;
  const int dB = T2_A + w * 1024;

  f32x4 acc[4][4];
  f32x4 zero = {0.f, 0.f, 0.f, 0.f};
#pragma unroll
  for (int mi = 0; mi < 4; mi++)
#pragma unroll
    for (int ni = 0; ni < 4; ni++) acc[mi][ni] = zero;

  int wr = w >> 1, wc = w & 1;
  int wm = wr * 64, wn = wc * 64;
  int lcol = lane & 15, quad = lane >> 4;
  int sx = (lcol & 7) << 3;

  auto STG = [&](int kt, int b) {
    uint16_t* lb = lds + b * T2_ELE;
    int ko = kt * 64;
#pragma unroll
    for (int c = 0; c < 4; c++) async_load16(srcA[c] + ko, lb + dA + c * 512);
#pragma unroll
    for (int c = 0; c < 2; c++) async_load16(srcB[c] + ko, lb + dB + c * 512);
  };

  STG(0, 0); STG(1, 1);
  WAIT_VM6();
  BARRIER();

  const int NT = I_DIM / 64;               // 64
  for (int t = 0; t < NT; ++t) {
    const int b = t % 3, b2 = (t + 2) % 3;
    uint16_t* lb  = lds + b * T2_ELE;
    uint16_t* lb2 = lds + b2 * T2_ELE;
    const bool pre = (t + 2 < NT);
    const int ko = (t + 2) * 64;

    // ---- phase 1 (ks = 0) ----
    {
      const int krs = (quad * 8) ^ sx;
      bf16x8 af[4], bb[4];
#pragma unroll
      for (int mi = 0; mi < 4; mi++)
        af[mi] = *(const bf16x8*)(lb + (wm + mi * 16 + lcol) * 64 + krs);
#pragma unroll
      for (int ni = 0; ni < 4; ni++)
        bb[ni] = *(const bf16x8*)(lb + T2_A + (wn + ni * 16 + lcol) * 64 + krs);
      if (pre) {
        async_load16(srcA[0] + ko, lb2 + dA + 0 * 512);
        async_load16(srcA[1] + ko, lb2 + dA + 1 * 512);
        async_load16(srcA[2] + ko, lb2 + dA + 2 * 512);
      }
      BARRIER();
      WAIT_LGKM0();
      __builtin_amdgcn_s_setprio(1);
#pragma unroll
      for (int mi = 0; mi < 4; mi++)
#pragma unroll
        for (int ni = 0; ni < 4; ni++)
          acc[mi][ni] = __builtin_amdgcn_mfma_f32_16x16x32_bf16(af[mi], bb[ni], acc[mi][ni], 0, 0, 0);
      __builtin_amdgcn_s_setprio(0);
      BARRIER();
    }
    // ---- phase 2 (ks = 1) ----
    {
      const int krs = (32 + quad * 8) ^ sx;
      bf16x8 af[4], bb[4];
#pragma unroll
      for (int mi = 0; mi < 4; mi++)
        af[mi] = *(const bf16x8*)(lb + (wm + mi * 16 + lcol) * 64 + krs);
#pragma unroll
      for (int ni = 0; ni < 4; ni++)
        bb[ni] = *(const bf16x8*)(lb + T2_A + (wn + ni * 16 + lcol) * 64 + krs);
      if (pre) {
        async_load16(srcA[3] + ko, lb2 + dA + 3 * 512);
        async_load16(srcB[0] + ko, lb2 + dB + 0 * 512);
        async_load16(srcB[1] + ko, lb2 + dB + 1 * 512);
      }
      BARRIER();
      WAIT_LGKM0();
      __builtin_amdgcn_s_setprio(1);
#pragma unroll
      for (int mi = 0; mi < 4; mi++)
#pragma unroll
        for (int ni = 0; ni < 4; ni++)
          acc[mi][ni] = __builtin_amdgcn_mfma_f32_16x16x32_bf16(af[mi], bb[ni], acc[mi][ni], 0, 0, 0);
      __builtin_amdgcn_s_setprio(0);
      if (pre) { WAIT_VM6(); } else { WAIT_VM0(); }
      BARRIER();
    }
  }

  int col0 = colBase + wn;
#pragma unroll
  for (int mi = 0; mi < 4; mi++) {
#pragma unroll
    for (int r = 0; r < 4; r++) {
      int localRow = by * 256 + wm + mi * 16 + quad * 4 + r;
      if (localRow < cnt) {
        size_t prow = (size_t)off + localRow;
        float wgt = pairw[prow];
        float* yr = y + prow * H_DIM + col0;
#pragma unroll
        for (int ni = 0; ni < 4; ni++)
          yr[ni * 16 + lcol] = acc[mi][ni][r] * wgt;
      }
    }
  }
}

// ---------------- combine: out[t] = y[slot(2t)] + y[slot(2t+1)] ----------------
__global__ void combine_kernel(const float* __restrict__ y, const int* __restrict__ slotOf,
                               float* __restrict__ out) {
  int t = blockIdx.x;
  int s0 = slotOf[2 * t], s1 = slotOf[2 * t + 1];
  int c = threadIdx.x * 8;
  const float4* a = (const float4*)(y + (size_t)s0 * H_DIM + c);
  const float4* b = (const float4*)(y + (size_t)s1 * H_DIM + c);
  float4 a0 = a[0], a1 = a[1], b0 = b[0], b1 = b[1];
  float4 o0 = {a0.x + b0.x, a0.y + b0.y, a0.z + b0.z, a0.w + b0.w};
  float4 o1 = {a1.x + b1.x, a1.y + b1.y, a1.z + b1.z, a1.w + b1.w};
  float4* dst = (float4*)(out + (size_t)t * H_DIM + c);
  dst[0] = o0; dst[1] = o1;
}

extern "C" void kernel_launch(void* const* d_in, const int* in_sizes, int n_in,
                              void* d_out, int out_size, void* d_ws, size_t ws_size,
                              hipStream_t stream) {
  const float* x    = (const float*)d_in[0];
  const int*   eidx = (const int*)d_in[1];
  const float* ew   = (const float*)d_in[2];
  const float* gate = (const float*)d_in[3];
  const float* up   = (const float*)d_in[4];
  const float* down = (const float*)d_in[5];
  float* out = (float*)d_out;
  char* ws = (char*)d_ws;

  if (ws_size < WS_FULL) {
    hipMemsetAsync(d_out, 0, (size_t)NTOK * H_DIM * sizeof(float), stream);
    return;
  }

  int*      counts  = (int*)(ws + WS_COUNTS);
  int*      offsets = (int*)(ws + WS_OFFSETS);
  int*      tokid   = (int*)(ws + WS_TOKID);
  int*      slotOf  = (int*)(ws + WS_SLOT);
  float*    pairw   = (float*)(ws + WS_PAIRW);
  uint16_t* xg      = (uint16_t*)(ws + WS_XG);
  uint16_t* inter   = (uint16_t*)(ws + WS_INTER);
  float*    y       = (float*)(ws + WS_Y);
  uint16_t* gw      = (uint16_t*)(ws + WS_GW);
  uint16_t* uw      = (uint16_t*)(ws + WS_UW);
  uint16_t* dwp     = (uint16_t*)(ws + WS_DW);

  route_kernel<<<1, 256, 0, stream>>>(eidx, ew, counts, offsets, tokid, slotOf, pairw);
  gather_cast_kernel<<<NPAIR, 256, 0, stream>>>(x, tokid, xg);
  cast3_kernel<<<dim3(2048, 3), 256, 0, stream>>>(gate, up, down, gw, uw, dwp);

  gemm1_v6<<<dim3(64 * 32 * NEXP), 512, 0, stream>>>(
      xg, gw, uw, counts, offsets, inter);
  gemm2_v6<<<dim3(16 * 32 * NEXP), 512, 0, stream>>>(
      inter, dwp, counts, offsets, pairw, y);
  combine_kernel<<<NTOK, 256, 0, stream>>>(y, slotOf, out);
}